// Round 8
// baseline (790.064 us; speedup 1.0000x reference)
//
#include <hip/hip_runtime.h>
#include <hip/hip_bf16.h>

using short8 = __attribute__((ext_vector_type(8))) short;
using f32x4  = __attribute__((ext_vector_type(4))) float;
using f32x16 = __attribute__((ext_vector_type(16))) float;

#define GLL16(g, l)                                                          \
  __builtin_amdgcn_global_load_lds(                                          \
      (const __attribute__((address_space(1))) void*)(g),                    \
      (__attribute__((address_space(3))) void*)(l), 16, 0, 0)

// ---------------------------------------------------------------------------
// Kernel 1: fused smooth-scale + block-128 fake quant, fp32 -> bf16
// ---------------------------------------------------------------------------
__global__ __launch_bounds__(256) void quant_kernel(
    const float* __restrict__ x, const float* __restrict__ smooth,
    __hip_bfloat16* __restrict__ xq, int D) {
  int tid = threadIdx.x;
  size_t qb = (size_t)blockIdx.x * 8 + (tid >> 5);
  int l = tid & 31;
  size_t base = qb * 128 + (size_t)l * 4;
  const float4 v = *(const float4*)(x + base);
  int d = (int)(base & (size_t)(D - 1));
  const float4 s = *(const float4*)(smooth + d);
  float y0 = v.x * s.x, y1 = v.y * s.y, y2 = v.z * s.z, y3 = v.w * s.w;
  float am = fmaxf(fmaxf(fabsf(y0), fabsf(y1)), fmaxf(fabsf(y2), fabsf(y3)));
#pragma unroll
  for (int off = 1; off < 32; off <<= 1)
    am = fmaxf(am, __shfl_xor(am, off, 64));
  float scale = fminf(fmaxf(am, 1e-12f) / 6.0f, 448.0f);
  float q0 = fminf(fmaxf(rintf(y0 / scale), -6.0f), 6.0f) * scale;
  float q1 = fminf(fmaxf(rintf(y1 / scale), -6.0f), 6.0f) * scale;
  float q2 = fminf(fmaxf(rintf(y2 / scale), -6.0f), 6.0f) * scale;
  float q3 = fminf(fmaxf(rintf(y3 / scale), -6.0f), 6.0f) * scale;
  union {
    __hip_bfloat16 h[4];
    uint2 u;
  } pk;
  pk.h[0] = __float2bfloat16(q0);
  pk.h[1] = __float2bfloat16(q1);
  pk.h[2] = __float2bfloat16(q2);
  pk.h[3] = __float2bfloat16(q3);
  *(uint2*)(xq + base) = pk.u;
}

// ---------------------------------------------------------------------------
// Kernel 2: W_eff = w_ternary + lora_b @ lora_a  (fp32 accum), cast to bf16.
// ---------------------------------------------------------------------------
__global__ __launch_bounds__(256) void wprep_kernel(
    const float* __restrict__ w, const float* __restrict__ la,
    const float* __restrict__ lb, __hip_bfloat16* __restrict__ weff, int Dk,
    int R) {
  __shared__ float lbs[16 * 64];
  int tid = threadIdx.x;
  int o0 = (blockIdx.x >> 4) * 16;
  int d = ((blockIdx.x & 15) << 8) + tid;
#pragma unroll
  for (int i = 0; i < 4; ++i) {
    int idx = tid + i * 256;
    lbs[idx] = lb[(size_t)(o0 + (idx >> 6)) * R + (idx & 63)];
  }
  __syncthreads();
  float acc[16];
#pragma unroll
  for (int oo = 0; oo < 16; ++oo) acc[oo] = 0.f;
  for (int r = 0; r < 64; ++r) {
    float av = la[(size_t)r * Dk + d];
#pragma unroll
    for (int oo = 0; oo < 16; ++oo) acc[oo] += lbs[oo * 64 + r] * av;
  }
#pragma unroll
  for (int oo = 0; oo < 16; ++oo) {
    size_t idx = (size_t)(o0 + oo) * Dk + d;
    weff[idx] = __float2bfloat16(w[idx] + acc[oo]);
  }
}

// ---------------------------------------------------------------------------
// Kernel 3: 256x256-tile 8-phase bf16 GEMM  (C = A * B^T + bias)
// R5 skeleton (proven race-free lockstep, 2 barriers/phase, vmcnt(6) at
// P4/P8) with:
//  * mfma_f32_32x32x16_bf16 (+15% pipe rate, 8 MFMA/phase vs 16)
//  * CHUNK-MAJOR LDS layout per 16KB half-tile: [c=0..7][r=0..127][16B].
//    A 32-row fragment read (fixed c, rows t*32+0..31) = 512 consecutive
//    bytes per 32-lane group -> conflict-free by construction (fixes R3's
//    5e7 conflicts).  global_load_lds keeps a LINEAR LDS dest; the per-lane
//    GLOBAL source is permuted to match: thread(w,l) issue j loads element
//    (r=(w&1)*64+l, c=j*4+(w>>1)) of the half-tile.
//  * R3-validated 32x32 C/D epilogue (col=lane&31, row=(r&3)+8*(r>>2)+
//    4*(lane>>5)).
// ---------------------------------------------------------------------------
#define BM 256
#define BN 256
#define BKT 64

__global__ __launch_bounds__(512, 2) void gemm_kernel(
    const __hip_bfloat16* __restrict__ A, const __hip_bfloat16* __restrict__ B,
    const float* __restrict__ bias, float* __restrict__ C, int M, int N,
    int K) {
  __shared__ __attribute__((aligned(16))) char lds[131072];

  const int tid = threadIdx.x;
  const int wave = tid >> 6, lane = tid & 63;
  const int wr = wave >> 2, wc = wave & 3;
  const int l31 = lane & 31;
  const int ksel = lane >> 5;

  // XCD-aware bijective swizzle (nwg % 8 == 0: 1024 blocks)
  const int nwg = gridDim.x;
  const int cpx = nwg >> 3;
  const int swzb = (blockIdx.x & 7) * cpx + (blockIdx.x >> 3);
  const int ntn = N / BN;
  const int tm = swzb / ntn, tn = swzb % ntn;
  const size_t m0 = (size_t)tm * BM, n0 = (size_t)tn * BN;

  // staging source permutation for chunk-major LDS:
  //   issue j of wave w, lane l  ->  (r, c) = ((w&1)*64 + l, j*4 + (w>>1))
  const int stg_row = (wave & 1) * 64 + lane;
  const int stg_c0 = (wave >> 1) * 8;  // elements
  const __hip_bfloat16* baseA = A + (m0 + stg_row) * (size_t)K + stg_c0;
  const __hip_bfloat16* baseB = B + (n0 + stg_row) * (size_t)K + stg_c0;
  char* sbase = lds + wave * 1024;  // linear wave-uniform LDS dest

  // fragment read bases (chunk-major): addr = region + (kk*2+ksel)*2048 +
  //   (row)*16;  A row = wr*64 + t2*32 + l31;  B row(col) = wc*32 + l31
  const char* rdA = lds + ksel * 2048 + (wr * 64 + l31) * 16;
  const char* rdB = lds + 32768 + ksel * 2048 + (wc * 32 + l31) * 16;

#define STAGE(d, ab, h, kt)                                                   \
  do {                                                                        \
    const __hip_bfloat16* _g = ((ab) ? baseB : baseA) +                       \
                               (size_t)((h) * 128) * K + (size_t)(kt) * BKT;  \
    char* _l = sbase + (d) * 65536 + (ab) * 32768 + (h) * 16384;              \
    GLL16(_g, _l);                                                            \
    GLL16(_g + 32, _l + 8192);                                                \
  } while (0)

#define READ_A32(DST, d, h)                                                   \
  _Pragma("unroll") for (int t2 = 0; t2 < 2; ++t2)                            \
      _Pragma("unroll") for (int kk = 0; kk < 4; ++kk)                        \
          DST[t2][kk] = *(const short8*)(rdA + (d) * 65536 + (h) * 16384 +    \
                                         kk * 4096 + t2 * 512);

#define READ_B32(DST, d, g)                                                   \
  _Pragma("unroll") for (int kk = 0; kk < 4; ++kk)                            \
      DST[kk] = *(const short8*)(rdB + (d) * 65536 + (g) * 16384 + kk * 4096);

#define MFMA8(h, g, AF, BF)                                                   \
  _Pragma("unroll") for (int kk = 0; kk < 4; ++kk)                            \
      _Pragma("unroll") for (int t2 = 0; t2 < 2; ++t2)                        \
          acc[h][t2][g] = __builtin_amdgcn_mfma_f32_32x32x16_bf16(            \
              AF[t2][kk], BF[kk], acc[h][t2][g], 0, 0, 0);

#define BARRIER __builtin_amdgcn_s_barrier()
#define SBAR0 __builtin_amdgcn_sched_barrier(0)
#define GATE                                                                  \
  asm volatile("s_waitcnt lgkmcnt(0)" ::: "memory");                          \
  __builtin_amdgcn_sched_barrier(0)
#define VMW6()                                                                \
  asm volatile("s_waitcnt vmcnt(6)" ::: "memory");                            \
  __builtin_amdgcn_sched_barrier(0)

  short8 aF0[2][4], aF1[2][4], bF0[4], bF1[4];
  f32x16 acc[2][2][2];
#pragma unroll
  for (int h = 0; h < 2; ++h)
#pragma unroll
    for (int t2 = 0; t2 < 2; ++t2)
#pragma unroll
      for (int g = 0; g < 2; ++g)
#pragma unroll
        for (int r = 0; r < 16; ++r) acc[h][t2][g][r] = 0.f;

  const int NK = K / BKT;  // 64

  // prologue: K0 (all 4 halves) -> buf0; K1 {A-h0, B-h1, A-h1} -> buf1
  STAGE(0, 0, 0, 0);
  STAGE(0, 1, 1, 0);
  STAGE(0, 0, 1, 0);
  STAGE(0, 1, 0, 0);
  STAGE(1, 0, 0, 1);
  STAGE(1, 1, 1, 1);
  STAGE(1, 0, 1, 1);
  VMW6();  // own buf0 loads retired
  BARRIER; // all waves' too -> buf0 region complete

  const int niter = NK / 2;  // 32
  for (int i = 0; i < niter; ++i) {
    const int k2 = (2 * i + 2 < NK) ? 2 * i + 2 : NK - 1;
    const int k3 = (2 * i + 3 < NK) ? 2 * i + 3 : NK - 1;
    // ---- K-tile 2i from buf0 ----
    // P1: (h0,g0)
    READ_A32(aF0, 0, 0);
    READ_B32(bF0, 0, 0);
    STAGE(1, 1, 0, 2 * i + 1);  // buf1.B-h0 for K-tile 2i+1
    BARRIER;
    GATE;
    __builtin_amdgcn_s_setprio(1);
    MFMA8(0, 0, aF0, bF0);
    __builtin_amdgcn_s_setprio(0);
    READ_B32(bF1, 0, 1);  // W1: buf0.B-g1 (region complete since prev P8)
    SBAR0;
    BARRIER;
    // P2: (h0,g1)
    STAGE(0, 0, 0, k2);  // buf0.A-h0 <- K(2i+2)
    BARRIER;
    GATE;
    __builtin_amdgcn_s_setprio(1);
    MFMA8(0, 1, aF0, bF1);
    __builtin_amdgcn_s_setprio(0);
    READ_A32(aF1, 0, 1);  // W2: buf0.A-h1
    SBAR0;
    BARRIER;
    // P3: (h1,g1)
    STAGE(0, 1, 1, k2);  // buf0.B-h1
    BARRIER;
    GATE;
    __builtin_amdgcn_s_setprio(1);
    MFMA8(1, 1, aF1, bF1);
    __builtin_amdgcn_s_setprio(0);
    SBAR0;
    BARRIER;
    // P4: (h1,g0)  (bF0 register-reused; zero ds_reads this phase)
    STAGE(0, 0, 1, k2);  // buf0.A-h1
    BARRIER;
    GATE;
    __builtin_amdgcn_s_setprio(1);
    MFMA8(1, 0, aF1, bF0);
    __builtin_amdgcn_s_setprio(0);
    VMW6();  // own buf1 loads retired; barrier completes region
    SBAR0;
    BARRIER;
    // ---- K-tile 2i+1 from buf1 ----
    // P5: (h0,g0)
    READ_A32(aF0, 1, 0);
    READ_B32(bF0, 1, 0);
    STAGE(0, 1, 0, k2);  // buf0.B-h0
    BARRIER;
    GATE;
    __builtin_amdgcn_s_setprio(1);
    MFMA8(0, 0, aF0, bF0);
    __builtin_amdgcn_s_setprio(0);
    READ_B32(bF1, 1, 1);  // W5: buf1.B-g1
    SBAR0;
    BARRIER;
    // P6: (h0,g1)
    STAGE(1, 0, 0, k3);  // buf1.A-h0 <- K(2i+3)
    BARRIER;
    GATE;
    __builtin_amdgcn_s_setprio(1);
    MFMA8(0, 1, aF0, bF1);
    __builtin_amdgcn_s_setprio(0);
    READ_A32(aF1, 1, 1);  // W6: buf1.A-h1
    SBAR0;
    BARRIER;
    // P7: (h1,g1)
    STAGE(1, 1, 1, k3);  // buf1.B-h1
    BARRIER;
    GATE;
    __builtin_amdgcn_s_setprio(1);
    MFMA8(1, 1, aF1, bF1);
    __builtin_amdgcn_s_setprio(0);
    SBAR0;
    BARRIER;
    // P8: (h1,g0)  (bF0 register-reused; zero ds_reads this phase)
    STAGE(1, 0, 1, k3);  // buf1.A-h1
    BARRIER;
    GATE;
    __builtin_amdgcn_s_setprio(1);
    MFMA8(1, 0, aF1, bF0);
    __builtin_amdgcn_s_setprio(0);
    VMW6();  // own buf0 loads retired; barrier completes region for next P1
    SBAR0;
    BARRIER;
  }

  // epilogue: 32x32 C/D layout  col=lane&31, row=(r&3)+8*(r>>2)+4*(lane>>5)
#pragma unroll
  for (int h = 0; h < 2; ++h)
#pragma unroll
    for (int t2 = 0; t2 < 2; ++t2)
#pragma unroll
      for (int g = 0; g < 2; ++g) {
        const int col = (int)n0 + g * 128 + wc * 32 + l31;
        const float bv = bias[col];
        const int row0 = (int)m0 + h * 128 + wr * 64 + t2 * 32 + ksel * 4;
#pragma unroll
        for (int r = 0; r < 16; ++r) {
          const int row = row0 + (r & 3) + 8 * (r >> 2);
          C[(size_t)row * N + col] = acc[h][t2][g][r] + bv;
        }
      }
}

// ---------------------------------------------------------------------------
extern "C" void kernel_launch(void* const* d_in, const int* in_sizes, int n_in,
                              void* d_out, int out_size, void* d_ws,
                              size_t ws_size, hipStream_t stream) {
  const float* x = (const float*)d_in[0];
  const float* w = (const float*)d_in[1];
  const float* smooth = (const float*)d_in[2];
  const float* la = (const float*)d_in[3];
  const float* lb = (const float*)d_in[4];
  const float* bias = (const float*)d_in[5];
  float* out = (float*)d_out;

  const int K = in_sizes[2];      // 4096
  const int N = in_sizes[5];      // 4096
  const int M = in_sizes[0] / K;  // 16384
  const int R = in_sizes[3] / K;  // 64

  __hip_bfloat16* xq = (__hip_bfloat16*)d_ws;
  __hip_bfloat16* weff = xq + (size_t)M * K;

  {
    size_t qblocks = ((size_t)M * K) / 128;
    int blocks = (int)(qblocks / 8);
    quant_kernel<<<blocks, 256, 0, stream>>>(x, smooth, xq, K);
  }
  {
    int blocks = (N / 16) * (K / 256);
    wprep_kernel<<<blocks, 256, 0, stream>>>(w, la, lb, weff, K, R);
  }
  {
    int blocks = (M / BM) * (N / BN);
    gemm_kernel<<<blocks, 512, 0, stream>>>(xq, weff, bias, out, M, N, K);
  }
}

// Round 9
// 621.321 us; speedup vs baseline: 1.2716x; 1.2716x over previous
//
#include <hip/hip_runtime.h>
#include <hip/hip_bf16.h>

using short8 = __attribute__((ext_vector_type(8))) short;
using f32x4  = __attribute__((ext_vector_type(4))) float;

#define GLL16(g, l)                                                          \
  __builtin_amdgcn_global_load_lds(                                          \
      (const __attribute__((address_space(1))) void*)(g),                    \
      (__attribute__((address_space(3))) void*)(l), 16, 0, 0)

// ---------------------------------------------------------------------------
// Kernel 1 (fused prep): blocks [0, nq) do smooth-scale + block-128 fake
// quant (fp32 -> bf16); blocks [nq, nq+nw) do W_eff = w + lora_b@lora_a.
// Independent outputs; fusing lets wprep co-schedule into quant's tail.
// ---------------------------------------------------------------------------
__global__ __launch_bounds__(256) void prep_kernel(
    const float* __restrict__ x, const float* __restrict__ smooth,
    __hip_bfloat16* __restrict__ xq, const float* __restrict__ w,
    const float* __restrict__ la, const float* __restrict__ lb,
    __hip_bfloat16* __restrict__ weff, int D, int R, int nq) {
  __shared__ float lbs[16 * 64];
  int tid = threadIdx.x;
  if ((int)blockIdx.x < nq) {
    // ---- quant part ----
    size_t qb = (size_t)blockIdx.x * 8 + (tid >> 5);
    int l = tid & 31;
    size_t base = qb * 128 + (size_t)l * 4;
    const float4 v = *(const float4*)(x + base);
    int d = (int)(base & (size_t)(D - 1));
    const float4 s = *(const float4*)(smooth + d);
    float y0 = v.x * s.x, y1 = v.y * s.y, y2 = v.z * s.z, y3 = v.w * s.w;
    float am = fmaxf(fmaxf(fabsf(y0), fabsf(y1)), fmaxf(fabsf(y2), fabsf(y3)));
#pragma unroll
    for (int off = 1; off < 32; off <<= 1)
      am = fmaxf(am, __shfl_xor(am, off, 64));
    float scale = fminf(fmaxf(am, 1e-12f) / 6.0f, 448.0f);
    float q0 = fminf(fmaxf(rintf(y0 / scale), -6.0f), 6.0f) * scale;
    float q1 = fminf(fmaxf(rintf(y1 / scale), -6.0f), 6.0f) * scale;
    float q2 = fminf(fmaxf(rintf(y2 / scale), -6.0f), 6.0f) * scale;
    float q3 = fminf(fmaxf(rintf(y3 / scale), -6.0f), 6.0f) * scale;
    union {
      __hip_bfloat16 h[4];
      uint2 u;
    } pk;
    pk.h[0] = __float2bfloat16(q0);
    pk.h[1] = __float2bfloat16(q1);
    pk.h[2] = __float2bfloat16(q2);
    pk.h[3] = __float2bfloat16(q3);
    *(uint2*)(xq + base) = pk.u;
  } else {
    // ---- wprep part ----
    int wb = (int)blockIdx.x - nq;
    int o0 = (wb >> 4) * 16;
    int d = ((wb & 15) << 8) + tid;
#pragma unroll
    for (int i = 0; i < 4; ++i) {
      int idx = tid + i * 256;
      lbs[idx] = lb[(size_t)(o0 + (idx >> 6)) * R + (idx & 63)];
    }
    __syncthreads();
    float acc[16];
#pragma unroll
    for (int oo = 0; oo < 16; ++oo) acc[oo] = 0.f;
    for (int r = 0; r < 64; ++r) {
      float av = la[(size_t)r * D + d];
#pragma unroll
      for (int oo = 0; oo < 16; ++oo) acc[oo] += lbs[oo * 64 + r] * av;
    }
#pragma unroll
    for (int oo = 0; oo < 16; ++oo) {
      size_t idx = (size_t)(o0 + oo) * D + d;
      weff[idx] = __float2bfloat16(w[idx] + acc[oo]);
    }
  }
}

// ---------------------------------------------------------------------------
// Kernel 2: 256x256-tile 8-phase bf16 GEMM  (C = A * B^T + bias)
// Byte-exact round-5 schedule — the proven local optimum of this structure:
// 16x16x32 MFMA, conflict-free swizzle (measured 0), vmcnt(6) at P4/P8,
// 2 barriers/phase lockstep, shadow reads W1/W2/W5/W6, B-frag register reuse.
// ---------------------------------------------------------------------------
#define BM 256
#define BN 256
#define BKT 64

__global__ __launch_bounds__(512, 2) void gemm_kernel(
    const __hip_bfloat16* __restrict__ A, const __hip_bfloat16* __restrict__ B,
    const float* __restrict__ bias, float* __restrict__ C, int M, int N,
    int K) {
  __shared__ __attribute__((aligned(16))) char lds[131072];

  const int tid = threadIdx.x;
  const int wave = tid >> 6, lane = tid & 63;
  const int wr = wave >> 2, wc = wave & 3;
  const int lr = lane & 15;
  const int hi16 = (lane >> 4) * 16;
  const int swx = (lr & 7) << 4;

  // XCD-aware bijective swizzle (nwg % 8 == 0: 1024 blocks)
  const int nwg = gridDim.x;
  const int cpx = nwg >> 3;
  const int swzb = (blockIdx.x & 7) * cpx + (blockIdx.x >> 3);
  const int ntn = N / BN;
  const int tm = swzb / ntn, tn = swzb % ntn;
  const size_t m0 = (size_t)tm * BM, n0 = (size_t)tn * BN;

  // staging: per-thread pre-swizzled global source; linear wave-uniform LDS dest
  const int trow = tid >> 3;
  const int csw = ((tid & 7) ^ (trow & 7)) * 8;
  const __hip_bfloat16* baseA = A + (m0 + trow) * (size_t)K + csw;
  const __hip_bfloat16* baseB = B + (n0 + trow) * (size_t)K + csw;
  char* sbase = lds + wave * 1024;

  // ds_read bases (per-lane, swizzled on read)
  const char* rdA = lds + (wr * 64 + lr) * 128;
  const char* rdB = lds + 32768 + (wc * 32 + lr) * 128;

#define STAGE(d, ab, h, kt)                                                   \
  do {                                                                        \
    const __hip_bfloat16* _g = ((ab) ? baseB : baseA) +                       \
                               (size_t)((h) * 128) * K + (size_t)(kt) * BKT;  \
    char* _l = sbase + (d) * 65536 + (ab) * 32768 + (h) * 16384;              \
    GLL16(_g, _l);                                                            \
    GLL16(_g + 64 * (size_t)K, _l + 8192);                                    \
  } while (0)

#define READ_A(DST, d, h)                                                     \
  _Pragma("unroll") for (int m = 0; m < 4; ++m)                               \
      _Pragma("unroll") for (int kk = 0; kk < 2; ++kk)                        \
          DST[m][kk] = *(const short8*)(rdA + (d) * 65536 + (h) * 16384 +     \
                                        m * 2048 + ((kk * 64 + hi16) ^ swx));

#define READ_B(DST, d, g)                                                     \
  _Pragma("unroll") for (int n = 0; n < 2; ++n)                               \
      _Pragma("unroll") for (int kk = 0; kk < 2; ++kk)                        \
          DST[n][kk] = *(const short8*)(rdB + (d) * 65536 + (g) * 16384 +     \
                                        n * 2048 + ((kk * 64 + hi16) ^ swx));

#define MFMA16(h, g, AF, BF)                                                  \
  _Pragma("unroll") for (int kk = 0; kk < 2; ++kk)                            \
      _Pragma("unroll") for (int m = 0; m < 4; ++m)                           \
          _Pragma("unroll") for (int n = 0; n < 2; ++n)                       \
              acc[h][m][g][n] = __builtin_amdgcn_mfma_f32_16x16x32_bf16(      \
                  AF[m][kk], BF[n][kk], acc[h][m][g][n], 0, 0, 0);

#define BARRIER __builtin_amdgcn_s_barrier()
#define SBAR0 __builtin_amdgcn_sched_barrier(0)
#define GATE                                                                  \
  asm volatile("s_waitcnt lgkmcnt(0)" ::: "memory");                          \
  __builtin_amdgcn_sched_barrier(0)
#define VMW6()                                                                \
  asm volatile("s_waitcnt vmcnt(6)" ::: "memory");                            \
  __builtin_amdgcn_sched_barrier(0)

  short8 aF0[4][2], aF1[4][2], bF0[2][2], bF1[2][2];
  f32x4 acc[2][4][2][2];
#pragma unroll
  for (int h = 0; h < 2; ++h)
#pragma unroll
    for (int m = 0; m < 4; ++m)
#pragma unroll
      for (int g = 0; g < 2; ++g)
#pragma unroll
        for (int n = 0; n < 2; ++n) acc[h][m][g][n] = (f32x4){0.f, 0.f, 0.f, 0.f};

  const int NK = K / BKT;  // 64

  // prologue: K0 (all 4 halves) -> buf0; K1 {A-h0, B-h1, A-h1} -> buf1
  STAGE(0, 0, 0, 0);
  STAGE(0, 1, 1, 0);
  STAGE(0, 0, 1, 0);
  STAGE(0, 1, 0, 0);
  STAGE(1, 0, 0, 1);
  STAGE(1, 1, 1, 1);
  STAGE(1, 0, 1, 1);
  VMW6();  // own buf0 loads retired
  BARRIER; // ... and every other wave's too -> buf0 region complete

  const int niter = NK / 2;  // 32
  for (int i = 0; i < niter; ++i) {
    const int k2 = (2 * i + 2 < NK) ? 2 * i + 2 : NK - 1;
    const int k3 = (2 * i + 3 < NK) ? 2 * i + 3 : NK - 1;
    // ---- K-tile 2i from buf0 ----
    // P1: (h0,g0)   [top reads: buf0 complete since prev-P8 VMW6+barrier]
    READ_A(aF0, 0, 0);
    READ_B(bF0, 0, 0);
    STAGE(1, 1, 0, 2 * i + 1);  // buf1.B-h0 for K-tile 2i+1
    BARRIER;
    GATE;
    __builtin_amdgcn_s_setprio(1);
    MFMA16(0, 0, aF0, bF0);
    __builtin_amdgcn_s_setprio(0);
    READ_B(bF1, 0, 1);  // W1: buf0.B-h1 (retired prev-P8 VMW6+barrier)
    SBAR0;
    BARRIER;
    // P2: (h0,g1)
    STAGE(0, 0, 0, k2);  // buf0.A-h0 <- K(2i+2)
    BARRIER;
    GATE;
    __builtin_amdgcn_s_setprio(1);
    MFMA16(0, 1, aF0, bF1);
    __builtin_amdgcn_s_setprio(0);
    READ_A(aF1, 0, 1);  // W2: buf0.A-h1 (retired prev-P8 VMW6+barrier)
    SBAR0;
    BARRIER;
    // P3: (h1,g1)
    STAGE(0, 1, 1, k2);  // buf0.B-h1
    BARRIER;
    GATE;
    __builtin_amdgcn_s_setprio(1);
    MFMA16(1, 1, aF1, bF1);
    __builtin_amdgcn_s_setprio(0);
    SBAR0;
    BARRIER;
    // P4: (h1,g0)  (bF0 register-reused; zero ds_reads this phase)
    STAGE(0, 0, 1, k2);  // buf0.A-h1
    BARRIER;
    GATE;
    __builtin_amdgcn_s_setprio(1);
    MFMA16(1, 0, aF1, bF0);
    __builtin_amdgcn_s_setprio(0);
    VMW6();  // own buf1 loads retired; barrier below completes the region
    SBAR0;
    BARRIER;
    // ---- K-tile 2i+1 from buf1 ----
    // P5: (h0,g0)   [top reads: buf1 complete since P4 VMW6+barrier]
    READ_A(aF0, 1, 0);
    READ_B(bF0, 1, 0);
    STAGE(0, 1, 0, k2);  // buf0.B-h0
    BARRIER;
    GATE;
    __builtin_amdgcn_s_setprio(1);
    MFMA16(0, 0, aF0, bF0);
    __builtin_amdgcn_s_setprio(0);
    READ_B(bF1, 1, 1);  // W5: buf1.B-h1 (retired P4 VMW6+barrier)
    SBAR0;
    BARRIER;
    // P6: (h0,g1)
    STAGE(1, 0, 0, k3);  // buf1.A-h0 <- K(2i+3)
    BARRIER;
    GATE;
    __builtin_amdgcn_s_setprio(1);
    MFMA16(0, 1, aF0, bF1);
    __builtin_amdgcn_s_setprio(0);
    READ_A(aF1, 1, 1);  // W6: buf1.A-h1 (retired P4 VMW6+barrier)
    SBAR0;
    BARRIER;
    // P7: (h1,g1)
    STAGE(1, 1, 1, k3);  // buf1.B-h1
    BARRIER;
    GATE;
    __builtin_amdgcn_s_setprio(1);
    MFMA16(1, 1, aF1, bF1);
    __builtin_amdgcn_s_setprio(0);
    SBAR0;
    BARRIER;
    // P8: (h1,g0)  (bF0 register-reused; zero ds_reads this phase)
    STAGE(1, 0, 1, k3);  // buf1.A-h1
    BARRIER;
    GATE;
    __builtin_amdgcn_s_setprio(1);
    MFMA16(1, 0, aF1, bF0);
    __builtin_amdgcn_s_setprio(0);
    VMW6();  // own buf0 loads retired; barrier completes region for next P1
    SBAR0;
    BARRIER;
  }

  // epilogue: C/D layout col=lane&15, row=(lane>>4)*4+reg
#pragma unroll
  for (int h = 0; h < 2; ++h)
#pragma unroll
    for (int g = 0; g < 2; ++g)
#pragma unroll
      for (int n = 0; n < 2; ++n) {
        const int col = (int)n0 + g * 128 + wc * 32 + n * 16 + lr;
        const float bv = bias[col];
#pragma unroll
        for (int m = 0; m < 4; ++m) {
          const int row = (int)m0 + h * 128 + wr * 64 + m * 16 + (lane >> 4) * 4;
#pragma unroll
          for (int r = 0; r < 4; ++r)
            C[(size_t)(row + r) * N + col] = acc[h][m][g][n][r] + bv;
        }
      }
}

// ---------------------------------------------------------------------------
extern "C" void kernel_launch(void* const* d_in, const int* in_sizes, int n_in,
                              void* d_out, int out_size, void* d_ws,
                              size_t ws_size, hipStream_t stream) {
  const float* x = (const float*)d_in[0];
  const float* w = (const float*)d_in[1];
  const float* smooth = (const float*)d_in[2];
  const float* la = (const float*)d_in[3];
  const float* lb = (const float*)d_in[4];
  const float* bias = (const float*)d_in[5];
  float* out = (float*)d_out;

  const int K = in_sizes[2];      // 4096
  const int N = in_sizes[5];      // 4096
  const int M = in_sizes[0] / K;  // 16384
  const int R = in_sizes[3] / K;  // 64

  __hip_bfloat16* xq = (__hip_bfloat16*)d_ws;
  __hip_bfloat16* weff = xq + (size_t)M * K;

  {
    int nq = (int)(((size_t)M * K) / 128 / 8);   // 65536
    int nw = (N / 16) * (K / 256);               // 4096
    prep_kernel<<<nq + nw, 256, 0, stream>>>(x, smooth, xq, w, la, lb, weff,
                                             K, R, nq);
  }
  {
    int blocks = (M / BM) * (N / BN);
    gemm_kernel<<<blocks, 512, 0, stream>>>(xq, weff, bias, out, M, N, K);
  }
}